// Round 22
// baseline (206.793 us; speedup 1.0000x reference)
//
#include <hip/hip_runtime.h>

#define DEVI __device__ __forceinline__

typedef short bf16x8 __attribute__((ext_vector_type(8)));
typedef short bf16x4 __attribute__((ext_vector_type(4)));
typedef float f32x4 __attribute__((ext_vector_type(4)));

constexpr int Bb = 8, TX = 1024, TC = 2048, CC = 512, NH = 8, HD = 64;
constexpr float LOG2E = 1.44269504f;

// fp32 -> bf16 round-to-nearest-even (values here are well-behaved, no NaN/Inf)
DEVI unsigned short f2bf(float f) {
  union { float f; unsigned u; } v; v.f = f;
  return (unsigned short)((v.u + 0x7FFFu + ((v.u >> 16) & 1u)) >> 16);
}

// packed f32x2 -> bf16x2 (low = lo, high = hi); no builtin on gfx950 (T12)
DEVI unsigned cvtpk(float lo, float hi) {
  unsigned r;
  asm("v_cvt_pk_bf16_f32 %0, %1, %2" : "=v"(r) : "v"(lo), "v"(hi));
  return r;
}

DEVI f32x4 mfma16(bf16x8 a, bf16x8 b, f32x4 c) {
  return __builtin_amdgcn_mfma_f32_16x16x32_bf16(a, b, c, 0, 0, 0);
}

DEVI f32x4 zero4() { f32x4 z = {0.f, 0.f, 0.f, 0.f}; return z; }

DEVI float max3f(float a, float b, float c) { return fmaxf(fmaxf(a, b), c); }

// async global->LDS, 16B per lane; LDS dest is wave-uniform base + lane*16,
// global source is per-lane (swizzled source = swizzled LDS layout, m173)
DEVI void gload_lds16(const unsigned short* g, unsigned short* l) {
  __builtin_amdgcn_global_load_lds(
      (const __attribute__((address_space(1))) void*)g,
      (__attribute__((address_space(3))) void*)l, 16, 0, 0);
}

// ---------------------------------------------------------------------------
// Fused fp32 -> bf16 convert for all 6 regions in ONE launch.
// ---------------------------------------------------------------------------
DEVI void cvt_region(const float* __restrict__ src,
                     unsigned short* __restrict__ dst, int n8, int i0, int stride) {
  for (int i = i0; i < n8; i += stride) {
    f32x4 a = *(const f32x4*)(src + (size_t)i * 8);
    f32x4 b = *(const f32x4*)(src + (size_t)i * 8 + 4);
    bf16x8 v;
#pragma unroll
    for (int j = 0; j < 4; j++) {
      v[j] = (short)f2bf(a[j]);
      v[j + 4] = (short)f2bf(b[j]);
    }
    *(bf16x8*)(dst + (size_t)i * 8) = v;
  }
}

__global__ __launch_bounds__(256) void cvt_all(
    const float* __restrict__ s0, unsigned short* __restrict__ d0, int n0,
    const float* __restrict__ s1, unsigned short* __restrict__ d1, int n1,
    const float* __restrict__ s2, unsigned short* __restrict__ d2, int n2,
    const float* __restrict__ s3, unsigned short* __restrict__ d3, int n3,
    const float* __restrict__ s4, unsigned short* __restrict__ d4, int n4,
    const float* __restrict__ s5, unsigned short* __restrict__ d5, int n5) {
  const int i0 = blockIdx.x * 256 + threadIdx.x;
  const int stride = gridDim.x * 256;
  cvt_region(s0, d0, n0, i0, stride);
  cvt_region(s1, d1, n1, i0, stride);
  cvt_region(s2, d2, n2, i0, stride);
  cvt_region(s3, d3, n3, i0, stride);
  cvt_region(s4, d4, n4, i0, stride);
  cvt_region(s5, d5, n5, i0, stride);
}

// ---------------------------------------------------------------------------
// 64x128-tile NT GEMM for the thin-M projections (Q-proj, O-proj).
// MODE 0: out bf16 permuted to (b,h,t,d).  MODE 1: out fp32 (r*512+c).
// ---------------------------------------------------------------------------
template <int MODE>
__global__ __launch_bounds__(256) void gemm64m(
    const unsigned short* __restrict__ A, const unsigned short* __restrict__ W,
    const float* __restrict__ bias, void* __restrict__ outp, int tlog2, float scale) {
  __shared__ __align__(16) unsigned short As[2][64 * 32];
  __shared__ __align__(16) unsigned short Bs[2][128 * 32];

  const int tid = threadIdx.x;
  const int wid = tid >> 6, l = tid & 63, l15 = l & 15, lhi = l >> 4;
  const int wm = wid >> 1, wn = wid & 1;
  const int mbase = blockIdx.y * 64, nbase = blockIdx.x * 128;

  f32x4 acc[2][4];
#pragma unroll
  for (int i = 0; i < 2; i++)
#pragma unroll
    for (int j = 0; j < 4; j++) acc[i][j] = zero4();

  auto stage = [&](int buf, int k0) {
    {  // A tile: 64 rows x 4 slots = 256 units, one per thread
      const int u = wid * 64 + l;
      const int row = u >> 2;
      const int gc = ((u & 3) ^ ((row >> 1) & 3)) * 8;
      gload_lds16(A + (size_t)(mbase + row) * CC + k0 + gc,
                  &As[buf][(wid * 64) * 8]);
    }
#pragma unroll
    for (int i = 0; i < 2; i++) {  // B tile: 128 rows x 4 slots = 512 units
      const int u = wid * 128 + i * 64 + l;
      const int row = u >> 2;
      const int gc = ((u & 3) ^ ((row >> 1) & 3)) * 8;
      gload_lds16(W + (size_t)(nbase + row) * CC + k0 + gc,
                  &Bs[buf][(wid * 128 + i * 64) * 8]);
    }
  };

  stage(0, 0);

  const int sA = (lhi ^ ((l15 >> 1) & 3)) << 3;

  constexpr int NK = CC / 32;
  for (int kt = 0; kt < NK; kt++) {
    const int cur = kt & 1;
    __syncthreads();
    if (kt + 1 < NK) stage(cur ^ 1, (kt + 1) * 32);

    bf16x8 af[2], bfr[4];
#pragma unroll
    for (int mi = 0; mi < 2; mi++)
      af[mi] = *(const bf16x8*)&As[cur][(wm * 32 + mi * 16 + l15) * 32 + sA];
#pragma unroll
    for (int ni = 0; ni < 4; ni++)
      bfr[ni] = *(const bf16x8*)&Bs[cur][(wn * 64 + ni * 16 + l15) * 32 + sA];
#pragma unroll
    for (int mi = 0; mi < 2; mi++)
#pragma unroll
      for (int ni = 0; ni < 4; ni++)
        acc[mi][ni] = mfma16(af[mi], bfr[ni], acc[mi][ni]);
  }

#pragma unroll
  for (int mi = 0; mi < 2; mi++)
#pragma unroll
    for (int ni = 0; ni < 4; ni++)
#pragma unroll
      for (int r = 0; r < 4; r++) {
        int grow = mbase + wm * 32 + mi * 16 + 4 * lhi + r;
        int gcol = nbase + wn * 64 + ni * 16 + l15;
        float val = (acc[mi][ni][r] + bias[gcol]) * scale;
        if (MODE == 0) {
          int T = 1 << tlog2;
          int bq = grow >> tlog2, tt = grow & (T - 1);
          int h = gcol >> 6, d = gcol & 63;
          size_t oidx = ((size_t)(bq * NH + h) * T + tt) * HD + d;
          ((unsigned short*)outp)[oidx] = f2bf(val);
        } else {
          ((float*)outp)[(size_t)grow * CC + gcol] = val;
        }
      }
}

// ---------------------------------------------------------------------------
// Fused K+V projection, 128x128 tile + global_load_lds: one A (ctx) tile
// feeds both Wk and Wv B-tiles (32 MFMA/K-step). K -> (b,h,t,d); V -> V^T.
// ---------------------------------------------------------------------------
__global__ __launch_bounds__(256, 2) void kv_gemm128(
    const unsigned short* __restrict__ A, const unsigned short* __restrict__ Wk,
    const unsigned short* __restrict__ Wv, const float* __restrict__ bk,
    const float* __restrict__ bv, unsigned short* __restrict__ k_out,
    unsigned short* __restrict__ v_out) {
  __shared__ __align__(16) unsigned short As[2][128 * 32];
  __shared__ __align__(16) unsigned short Bks[2][128 * 32];
  __shared__ __align__(16) unsigned short Bvs[2][128 * 32];

  const int tid = threadIdx.x;
  const int wid = tid >> 6, l = tid & 63, l15 = l & 15, lhi = l >> 4;
  const int wm = wid >> 1, wn = wid & 1;
  const int mbase = blockIdx.y * 128, nbase = blockIdx.x * 128;

  f32x4 acck[4][4], accv[4][4];
#pragma unroll
  for (int i = 0; i < 4; i++)
#pragma unroll
    for (int j = 0; j < 4; j++) { acck[i][j] = zero4(); accv[i][j] = zero4(); }

  auto stage = [&](int buf, int k0) {
#pragma unroll
    for (int i = 0; i < 2; i++) {
      const int u = wid * 128 + i * 64 + l;
      const int row = u >> 2;
      const int gc = ((u & 3) ^ ((row >> 1) & 3)) * 8;
      const int lo = (wid * 128 + i * 64) * 8;
      gload_lds16(A + (size_t)(mbase + row) * CC + k0 + gc, &As[buf][lo]);
      gload_lds16(Wk + (size_t)(nbase + row) * CC + k0 + gc, &Bks[buf][lo]);
      gload_lds16(Wv + (size_t)(nbase + row) * CC + k0 + gc, &Bvs[buf][lo]);
    }
  };

  stage(0, 0);

  const int sA = (lhi ^ ((l15 >> 1) & 3)) << 3;

  constexpr int NK = CC / 32;
  for (int kt = 0; kt < NK; kt++) {
    const int cur = kt & 1;
    __syncthreads();
    if (kt + 1 < NK) stage(cur ^ 1, (kt + 1) * 32);

    bf16x8 af[4], kf[4], vf[4];
#pragma unroll
    for (int mi = 0; mi < 4; mi++)
      af[mi] = *(const bf16x8*)&As[cur][(wm * 64 + mi * 16 + l15) * 32 + sA];
#pragma unroll
    for (int ni = 0; ni < 4; ni++) {
      kf[ni] = *(const bf16x8*)&Bks[cur][(wn * 64 + ni * 16 + l15) * 32 + sA];
      vf[ni] = *(const bf16x8*)&Bvs[cur][(wn * 64 + ni * 16 + l15) * 32 + sA];
    }
#pragma unroll
    for (int mi = 0; mi < 4; mi++)
#pragma unroll
      for (int ni = 0; ni < 4; ni++) {
        acck[mi][ni] = mfma16(af[mi], kf[ni], acck[mi][ni]);
        accv[mi][ni] = mfma16(af[mi], vf[ni], accv[mi][ni]);
      }
  }

#pragma unroll
  for (int mi = 0; mi < 4; mi++)
#pragma unroll
    for (int ni = 0; ni < 4; ni++)
#pragma unroll
      for (int r = 0; r < 4; r++) {
        int grow = mbase + wm * 64 + mi * 16 + 4 * lhi + r;
        int gcol = nbase + wn * 64 + ni * 16 + l15;
        int bq = grow >> 11, tt = grow & (TC - 1);
        int h = gcol >> 6, d = gcol & 63;
        float kv = acck[mi][ni][r] + bk[gcol];
        float vv = accv[mi][ni][r] + bv[gcol];
        k_out[((size_t)(bq * NH + h) * TC + tt) * HD + d] = f2bf(kv);
        v_out[((size_t)(bq * NH + h) * HD + d) * TC + tt] = f2bf(vv);
      }
}

// ---------------------------------------------------------------------------
// Flash attention fwd v11 — v10 + one-tile-lagged softmax pipeline (T15
// mechanism): iteration kt computes QK(kt) into sn[] while the softmax+PV of
// tile kt-1 (saved in sp[], +16 VGPR on a 44-VGPR kernel) runs — the two are
// data-independent, so MFMA and VALU co-issue within a wave instead of the
// old strict QK->softmax->PV serial chain. vtl becomes 3-buffered (PV lags 1
// tile; tile t in vtl[t%3]: writer iter t-1, reader iter t+1, next writer
// iter t+2 — barrier-separated; in-iteration commit (kt+1)%3 != PV (kt-1)%3).
// ktl stays 2-buffered. One barrier/iter. LDS 40KB (grid caps 2 blocks/CU
// anyway). Priming iter runs QK(0) only; epilogue finishes tile NT-1.
// Rest unchanged: XCD swizzle, swapped-QK^T, ones-MFMA row-sum, max3 tree,
// XOR-swizzled tiles, exp2, defer-max, setprio.
// ---------------------------------------------------------------------------
__global__ __launch_bounds__(512) void attn_fwd(
    const unsigned short* __restrict__ Qw, const unsigned short* __restrict__ Kw,
    const unsigned short* __restrict__ Vtw, unsigned short* __restrict__ y_pre,
    float* __restrict__ m_ws, float* __restrict__ il_ws) {
  __shared__ __align__(16) unsigned short ktl[2][64 * 64];  // [buf][key][d] swz
  __shared__ __align__(16) unsigned short vtl[3][64 * 64];  // [buf][d][key] swz

  const int tid = threadIdx.x;
  const int wid = tid >> 6, l = tid & 63, l15 = l & 15, lhi = l >> 4;
  // XCD swizzle: linear id -> (qg,h,b) with XCD = p%8 = b
  const int p = blockIdx.x + (TX / 128) * (blockIdx.y + NH * blockIdx.z);
  const int qg = p >> 6, h = (p >> 3) & 7, b = p & 7;
  const int qbase = qg * 128 + wid * 16;

  const unsigned short* Qh = Qw + (size_t)(b * NH + h) * TX * HD;
  const unsigned short* Kh = Kw + (size_t)(b * NH + h) * TC * HD;
  const unsigned short* Vt = Vtw + (size_t)(b * NH + h) * TC * HD;  // (d, t)

  bf16x8 aq0 = *(const bf16x8*)(Qh + (size_t)(qbase + l15) * HD + lhi * 8);
  bf16x8 aq1 = *(const bf16x8*)(Qh + (size_t)(qbase + l15) * HD + 32 + lhi * 8);

  bf16x8 ones;
#pragma unroll
  for (int j = 0; j < 8; j++) ones[j] = (short)0x3F80;  // bf16 1.0

  f32x4 accy[4];
#pragma unroll
  for (int db = 0; db < 4; db++) accy[db] = zero4();
  f32x4 accl = zero4();  // P-row-sum accumulator (ones-MFMA)
  float mrun = -1e30f;

  const int sl0 = l15 + ((lhi & 1) << 5);
  const int sl1 = sl0 + 16;
  const bool sel = ((lhi >> 1) & 1) != 0;

  const int rs0 = (lhi ^ (l15 & 7)) << 3;
  const int rs1 = ((lhi ^ 4) ^ (l15 & 7)) << 3;

  const int sr = tid >> 3;
  const int ssw = ((tid & 7) ^ (sr & 7)) << 3;
  const int sc0 = (tid & 7) * 8;

  // prologue: tile 0 -> LDS buffers 0
  bf16x8 kr = *(const bf16x8*)(Kh + (size_t)sr * HD + sc0);
  bf16x8 vp = *(const bf16x8*)(Vt + (size_t)sr * TC + sc0);
  *(bf16x8*)&ktl[0][sr * 64 + ssw] = kr;
  *(bf16x8*)&vtl[0][sr * 64 + ssw] = vp;
  __syncthreads();

  f32x4 sp[4];  // scores of the lagging tile (kt-1)

  // softmax + PV of the tile whose scores are in sp[]; V tile in vtl[vbuf]
  auto soft_pv = [&](int vbuf) {
    float t0 = max3f(sp[0][0], sp[0][1], sp[0][2]);
    float t1 = max3f(sp[0][3], sp[1][0], sp[1][1]);
    float t2 = max3f(sp[1][2], sp[1][3], sp[2][0]);
    float t3 = max3f(sp[2][1], sp[2][2], sp[2][3]);
    float t4 = max3f(sp[3][0], sp[3][1], sp[3][2]);
    float mx = fmaxf(max3f(t0, t1, t2), max3f(t3, t4, sp[3][3]));
    mx = fmaxf(mx, __shfl_xor(mx, 16));
    mx = fmaxf(mx, __shfl_xor(mx, 32));

    if (__any(mx - mrun > 7.0f)) {
      float mn = fmaxf(mrun, mx);
      float sc = exp2f(mrun - mn);
      mrun = mn;
#pragma unroll
      for (int r = 0; r < 4; r++) accl[r] *= sc;
#pragma unroll
      for (int db = 0; db < 4; db++)
#pragma unroll
        for (int r = 0; r < 4; r++) accy[db][r] *= sc;
    }

    float p4[4][4];
#pragma unroll
    for (int kb = 0; kb < 4; kb++)
#pragma unroll
      for (int r = 0; r < 4; r++) p4[kb][r] = exp2f(sp[kb][r] - mrun);

    unsigned pkw[4][2];
#pragma unroll
    for (int kb = 0; kb < 4; kb++) {
      pkw[kb][0] = cvtpk(p4[kb][0], p4[kb][1]);
      pkw[kb][1] = cvtpk(p4[kb][2], p4[kb][3]);
    }
    unsigned a00 = (unsigned)__shfl((int)pkw[0][0], sl0);
    unsigned a01 = (unsigned)__shfl((int)pkw[0][1], sl0);
    unsigned a10 = (unsigned)__shfl((int)pkw[1][0], sl0);
    unsigned a11 = (unsigned)__shfl((int)pkw[1][1], sl0);
    unsigned c00 = (unsigned)__shfl((int)pkw[0][0], sl1);
    unsigned c01 = (unsigned)__shfl((int)pkw[0][1], sl1);
    unsigned c10 = (unsigned)__shfl((int)pkw[1][0], sl1);
    unsigned c11 = (unsigned)__shfl((int)pkw[1][1], sl1);
    unsigned e00 = (unsigned)__shfl((int)pkw[2][0], sl0);
    unsigned e01 = (unsigned)__shfl((int)pkw[2][1], sl0);
    unsigned e10 = (unsigned)__shfl((int)pkw[3][0], sl0);
    unsigned e11 = (unsigned)__shfl((int)pkw[3][1], sl0);
    unsigned g00 = (unsigned)__shfl((int)pkw[2][0], sl1);
    unsigned g01 = (unsigned)__shfl((int)pkw[2][1], sl1);
    unsigned g10 = (unsigned)__shfl((int)pkw[3][0], sl1);
    unsigned g11 = (unsigned)__shfl((int)pkw[3][1], sl1);
    union { unsigned u[4]; bf16x8 v; } B0, B1;
    B0.u[0] = sel ? a10 : a00;
    B0.u[1] = sel ? a11 : a01;
    B0.u[2] = sel ? c10 : c00;
    B0.u[3] = sel ? c11 : c01;
    B1.u[0] = sel ? e10 : e00;
    B1.u[1] = sel ? e11 : e01;
    B1.u[2] = sel ? g10 : g00;
    B1.u[3] = sel ? g11 : g01;

    __builtin_amdgcn_s_setprio(1);
#pragma unroll
    for (int db = 0; db < 4; db++) {
      bf16x8 bv0 = *(const bf16x8*)&vtl[vbuf][(db * 16 + l15) * 64 + rs0];
      bf16x8 bv1 = *(const bf16x8*)&vtl[vbuf][(db * 16 + l15) * 64 + rs1];
      accy[db] = mfma16(bv0, B0.v, accy[db]);
      accy[db] = mfma16(bv1, B1.v, accy[db]);
    }
    accl = mfma16(ones, B0.v, accl);
    accl = mfma16(ones, B1.v, accl);
    __builtin_amdgcn_s_setprio(0);
  };

  constexpr int NT = TC / 64;

  // priming iteration (kt = 0): QK(0) only; commit tile 1
  {
    kr = *(const bf16x8*)(Kh + (size_t)(64 + sr) * HD + sc0);
    vp = *(const bf16x8*)(Vt + (size_t)sr * TC + 64 + sc0);
    __builtin_amdgcn_s_setprio(1);
#pragma unroll
    for (int kb = 0; kb < 4; kb++) {
      bf16x8 bk0 = *(const bf16x8*)&ktl[0][(kb * 16 + l15) * 64 + rs0];
      bf16x8 bk1 = *(const bf16x8*)&ktl[0][(kb * 16 + l15) * 64 + rs1];
      f32x4 a = zero4();
      a = mfma16(bk0, aq0, a);
      a = mfma16(bk1, aq1, a);
      sp[kb] = a;
    }
    __builtin_amdgcn_s_setprio(0);
    *(bf16x8*)&ktl[1][sr * 64 + ssw] = kr;
    *(bf16x8*)&vtl[1][sr * 64 + ssw] = vp;
    __syncthreads();
  }

  for (int kt = 1; kt < NT; kt++) {
    const int kcur = kt & 1;

    // 1. prefetch issue for tile kt+1 (oldest ops)
    if (kt + 1 < NT) {
      const int keyn = (kt + 1) * 64;
      kr = *(const bf16x8*)(Kh + (size_t)(keyn + sr) * HD + sc0);
      vp = *(const bf16x8*)(Vt + (size_t)sr * TC + keyn + sc0);
    }

    // 2. QK(kt) -> sn (independent of sp's softmax below -> pipes co-issue)
    f32x4 sn[4];
    __builtin_amdgcn_s_setprio(1);
#pragma unroll
    for (int kb = 0; kb < 4; kb++) {
      bf16x8 bk0 = *(const bf16x8*)&ktl[kcur][(kb * 16 + l15) * 64 + rs0];
      bf16x8 bk1 = *(const bf16x8*)&ktl[kcur][(kb * 16 + l15) * 64 + rs1];
      f32x4 a = zero4();
      a = mfma16(bk0, aq0, a);
      a = mfma16(bk1, aq1, a);
      sn[kb] = a;
    }
    __builtin_amdgcn_s_setprio(0);

    // 3. softmax + PV of tile kt-1
    soft_pv((kt - 1) % 3);

    // 4. rotate score buffers
#pragma unroll
    for (int kb = 0; kb < 4; kb++) sp[kb] = sn[kb];

    // 5. commit prefetch (tile kt+1)
    if (kt + 1 < NT) {
      *(bf16x8*)&ktl[(kt + 1) & 1][sr * 64 + ssw] = kr;
      *(bf16x8*)&vtl[(kt + 1) % 3][sr * 64 + ssw] = vp;
    }
    __syncthreads();
  }

  // epilogue: finish tile NT-1
  soft_pv((NT - 1) % 3);

  const float il = 1.f / accl[0];

#pragma unroll
  for (int db = 0; db < 4; db++) {
    bf16x4 o;
#pragma unroll
    for (int r = 0; r < 4; r++) o[r] = (short)f2bf(accy[db][r] * il);
    *(bf16x4*)(y_pre + (size_t)(b * TX + qbase + l15) * CC + h * HD + db * 16 +
               4 * lhi) = o;
  }
  if (lhi == 0) {
    int idx = (b * NH + h) * TX + qbase + l15;
    m_ws[idx] = mrun;
    il_ws[idx] = il;
  }
}

// ---------------------------------------------------------------------------
// att_mean v6 — FINAL (R15 spill, R17 occupancy, R20 spill; this operating
// point — KVBLK=64, 2-state Q, ~104 VGPR, 16KB LDS — is the feasibility
// pocket). 8 waves / 512 threads = 128 q-rows x 64 keys; per-head K tile in
// XOR-swizzled LDS (double-buffered, prefetch top / commit bottom, one
// barrier per head); p = 2^(s-m) * (1/l).
// ---------------------------------------------------------------------------
__global__ __launch_bounds__(512) void att_mean_k(
    const unsigned short* __restrict__ Qw, const unsigned short* __restrict__ Kw,
    const float* __restrict__ m_ws, const float* __restrict__ il_ws,
    float* __restrict__ attm) {
  __shared__ __align__(16) unsigned short ktl[2][64 * 64];  // [buf][key][d] swz

  const int tid = threadIdx.x;
  const int wid = tid >> 6, l = tid & 63, l15 = l & 15, lhi = l >> 4;
  const int qbase = blockIdx.x * 128 + wid * 16;  // x = q tile (fastest)
  const int keyb = blockIdx.y * 64;               // y = key tile
  const int b = blockIdx.z;

  const unsigned short* Qb = Qw + (size_t)b * NH * TX * HD;
  const unsigned short* Kb = Kw + (size_t)b * NH * TC * HD;

  const int rs0 = (lhi ^ (l15 & 7)) << 3;
  const int rs1 = ((lhi ^ 4) ^ (l15 & 7)) << 3;

  const int sr = tid >> 3;
  const int ssw = ((tid & 7) ^ (sr & 7)) << 3;
  const int sc0 = (tid & 7) * 8;

  bf16x8 aq0[2], aq1[2];
  f32x4 mm[2], ii[2];

  auto load_q = [&](int h, int p) {
    const unsigned short* qp =
        Qb + ((size_t)h * TX + qbase + l15) * HD + lhi * 8;
    aq0[p] = *(const bf16x8*)qp;
    aq1[p] = *(const bf16x8*)(qp + 32);
    mm[p] = *(const f32x4*)(m_ws + (size_t)(b * NH + h) * TX + qbase + 4 * lhi);
    ii[p] = *(const f32x4*)(il_ws + (size_t)(b * NH + h) * TX + qbase + 4 * lhi);
  };

  bf16x8 kr = *(const bf16x8*)(Kb + ((size_t)keyb + sr) * HD + sc0);
  load_q(0, 0);
  *(bf16x8*)&ktl[0][sr * 64 + ssw] = kr;
  __syncthreads();

  f32x4 am[4];
#pragma unroll
  for (int kb = 0; kb < 4; kb++) am[kb] = zero4();

#pragma unroll
  for (int h = 0; h < NH; h++) {
    const int cur = h & 1;

    if (h + 1 < NH) {
      kr = *(const bf16x8*)(Kb + ((size_t)(h + 1) * TC + keyb + sr) * HD + sc0);
      load_q(h + 1, cur ^ 1);
    }

#pragma unroll
    for (int kb = 0; kb < 4; kb++) {
      bf16x8 bk0 = *(const bf16x8*)&ktl[cur][(kb * 16 + l15) * 64 + rs0];
      bf16x8 bk1 = *(const bf16x8*)&ktl[cur][(kb * 16 + l15) * 64 + rs1];
      f32x4 a = zero4();
      a = mfma16(aq0[cur], bk0, a);
      a = mfma16(aq1[cur], bk1, a);
#pragma unroll
      for (int r = 0; r < 4; r++)
        am[kb][r] += exp2f(a[r] - mm[cur][r]) * ii[cur][r];
    }

    if (h + 1 < NH) {
      const int nxt = cur ^ 1;
      *(bf16x8*)&ktl[nxt][sr * 64 + ssw] = kr;
    }
    __syncthreads();
  }

#pragma unroll
  for (int kb = 0; kb < 4; kb++)
#pragma unroll
    for (int r = 0; r < 4; r++) {
      int trow = qbase + 4 * lhi + r;
      attm[(size_t)(b * TX + trow) * TC + keyb + kb * 16 + l15] = am[kb][r] * 0.125f;
    }
}

// ---------------------------------------------------------------------------
extern "C" void kernel_launch(void* const* d_in, const int* in_sizes, int n_in,
                              void* d_out, int out_size, void* d_ws, size_t ws_size,
                              hipStream_t stream) {
  const float* x   = (const float*)d_in[0];
  const float* ctx = (const float*)d_in[1];
  const float* Wq  = (const float*)d_in[2];
  const float* bq  = (const float*)d_in[3];
  const float* Wk  = (const float*)d_in[4];
  const float* bk  = (const float*)d_in[5];
  const float* Wv  = (const float*)d_in[6];
  const float* bv  = (const float*)d_in[7];
  const float* Wo  = (const float*)d_in[8];
  const float* bo  = (const float*)d_in[9];

  float* y_out = (float*)d_out;                       // (B, Tx, C)
  float* attm  = y_out + (size_t)Bb * TX * CC;        // (B, Tx, Tc)

  // workspace layout (16B-aligned), ~53 MB total:
  unsigned short* q_ws = (unsigned short*)d_ws;                  // B*NH*TX*HD bf16
  unsigned short* k_ws = q_ws + (size_t)Bb * NH * TX * HD;       // B*NH*TC*HD bf16
  unsigned short* v_ws = k_ws + (size_t)Bb * NH * TC * HD;       // B*NH*TC*HD bf16 (V^T)
  float* m_ws  = (float*)(v_ws + (size_t)Bb * NH * TC * HD);     // B*NH*TX f32
  float* il_ws = m_ws + (size_t)Bb * NH * TX;                    // B*NH*TX f32
  unsigned short* y_pre = (unsigned short*)(il_ws + (size_t)Bb * NH * TX);  // B*TX*CC bf16
  unsigned short* wb = y_pre + (size_t)Bb * TX * CC;             // 4x CC*CC bf16
  unsigned short* wbq = wb, *wbk = wb + CC * CC, *wbv = wb + 2 * CC * CC,
                 *wbo = wb + 3 * CC * CC;

  // bf16 input overlays (consumed before their regions are overwritten):
  unsigned short* xb = k_ws;              // read by Q-GEMM, then kv_gemm overwrites
  unsigned short* cb = (unsigned short*)attm;  // read by kv_gemm, att_mean_k overwrites

  const int NX8 = Bb * TX * CC / 8, NC8 = Bb * TC * CC / 8, NW8 = CC * CC / 8;
  cvt_all<<<dim3(2048), 256, 0, stream>>>(x, xb, NX8, ctx, cb, NC8,
                                          Wq, wbq, NW8, Wk, wbk, NW8,
                                          Wv, wbv, NW8, Wo, wbo, NW8);

  // Q pre-scaled by log2(e)/sqrt(hd) so attention exp is bare v_exp_f32 (2^x)
  gemm64m<0><<<dim3(CC / 128, (Bb * TX) / 64), 256, 0, stream>>>(
      xb, wbq, bq, q_ws, 10, 0.125f * LOG2E);
  kv_gemm128<<<dim3(CC / 128, (Bb * TC) / 128), 256, 0, stream>>>(
      cb, wbk, wbv, bk, bv, k_ws, v_ws);
  attn_fwd<<<dim3(TX / 128, NH, Bb), 512, 0, stream>>>(q_ws, k_ws, v_ws, y_pre, m_ws, il_ws);
  att_mean_k<<<dim3(TX / 128, TC / 64, Bb), 512, 0, stream>>>(q_ws, k_ws, m_ws, il_ws, attm);
  gemm64m<1><<<dim3(CC / 128, (Bb * TX) / 64), 256, 0, stream>>>(
      y_pre, wbo, bo, y_out, 10, 1.0f);
}

// Round 23
// 204.970 us; speedup vs baseline: 1.0089x; 1.0089x over previous
//
#include <hip/hip_runtime.h>

#define DEVI __device__ __forceinline__

typedef short bf16x8 __attribute__((ext_vector_type(8)));
typedef short bf16x4 __attribute__((ext_vector_type(4)));
typedef float f32x4 __attribute__((ext_vector_type(4)));

constexpr int Bb = 8, TX = 1024, TC = 2048, CC = 512, NH = 8, HD = 64;
constexpr float LOG2E = 1.44269504f;

// fp32 -> bf16 round-to-nearest-even (values here are well-behaved, no NaN/Inf)
DEVI unsigned short f2bf(float f) {
  union { float f; unsigned u; } v; v.f = f;
  return (unsigned short)((v.u + 0x7FFFu + ((v.u >> 16) & 1u)) >> 16);
}

// packed f32x2 -> bf16x2 (low = lo, high = hi); no builtin on gfx950 (T12)
DEVI unsigned cvtpk(float lo, float hi) {
  unsigned r;
  asm("v_cvt_pk_bf16_f32 %0, %1, %2" : "=v"(r) : "v"(lo), "v"(hi));
  return r;
}

DEVI f32x4 mfma16(bf16x8 a, bf16x8 b, f32x4 c) {
  return __builtin_amdgcn_mfma_f32_16x16x32_bf16(a, b, c, 0, 0, 0);
}

DEVI f32x4 zero4() { f32x4 z = {0.f, 0.f, 0.f, 0.f}; return z; }

DEVI float max3f(float a, float b, float c) { return fmaxf(fmaxf(a, b), c); }

// async global->LDS, 16B per lane; LDS dest is wave-uniform base + lane*16,
// global source is per-lane (swizzled source = swizzled LDS layout, m173)
DEVI void gload_lds16(const unsigned short* g, unsigned short* l) {
  __builtin_amdgcn_global_load_lds(
      (const __attribute__((address_space(1))) void*)g,
      (__attribute__((address_space(3))) void*)l, 16, 0, 0);
}

// ---------------------------------------------------------------------------
// Fused fp32 -> bf16 convert for all 6 regions in ONE launch.
// ---------------------------------------------------------------------------
DEVI void cvt_region(const float* __restrict__ src,
                     unsigned short* __restrict__ dst, int n8, int i0, int stride) {
  for (int i = i0; i < n8; i += stride) {
    f32x4 a = *(const f32x4*)(src + (size_t)i * 8);
    f32x4 b = *(const f32x4*)(src + (size_t)i * 8 + 4);
    bf16x8 v;
#pragma unroll
    for (int j = 0; j < 4; j++) {
      v[j] = (short)f2bf(a[j]);
      v[j + 4] = (short)f2bf(b[j]);
    }
    *(bf16x8*)(dst + (size_t)i * 8) = v;
  }
}

__global__ __launch_bounds__(256) void cvt_all(
    const float* __restrict__ s0, unsigned short* __restrict__ d0, int n0,
    const float* __restrict__ s1, unsigned short* __restrict__ d1, int n1,
    const float* __restrict__ s2, unsigned short* __restrict__ d2, int n2,
    const float* __restrict__ s3, unsigned short* __restrict__ d3, int n3,
    const float* __restrict__ s4, unsigned short* __restrict__ d4, int n4,
    const float* __restrict__ s5, unsigned short* __restrict__ d5, int n5) {
  const int i0 = blockIdx.x * 256 + threadIdx.x;
  const int stride = gridDim.x * 256;
  cvt_region(s0, d0, n0, i0, stride);
  cvt_region(s1, d1, n1, i0, stride);
  cvt_region(s2, d2, n2, i0, stride);
  cvt_region(s3, d3, n3, i0, stride);
  cvt_region(s4, d4, n4, i0, stride);
  cvt_region(s5, d5, n5, i0, stride);
}

// ---------------------------------------------------------------------------
// 64x128-tile NT GEMM for the thin-M projections (Q-proj, O-proj).
// MODE 0: out bf16 permuted to (b,h,t,d).  MODE 1: out fp32 (r*512+c).
// ---------------------------------------------------------------------------
template <int MODE>
__global__ __launch_bounds__(256) void gemm64m(
    const unsigned short* __restrict__ A, const unsigned short* __restrict__ W,
    const float* __restrict__ bias, void* __restrict__ outp, int tlog2, float scale) {
  __shared__ __align__(16) unsigned short As[2][64 * 32];
  __shared__ __align__(16) unsigned short Bs[2][128 * 32];

  const int tid = threadIdx.x;
  const int wid = tid >> 6, l = tid & 63, l15 = l & 15, lhi = l >> 4;
  const int wm = wid >> 1, wn = wid & 1;
  const int mbase = blockIdx.y * 64, nbase = blockIdx.x * 128;

  f32x4 acc[2][4];
#pragma unroll
  for (int i = 0; i < 2; i++)
#pragma unroll
    for (int j = 0; j < 4; j++) acc[i][j] = zero4();

  auto stage = [&](int buf, int k0) {
    {  // A tile: 64 rows x 4 slots = 256 units, one per thread
      const int u = wid * 64 + l;
      const int row = u >> 2;
      const int gc = ((u & 3) ^ ((row >> 1) & 3)) * 8;
      gload_lds16(A + (size_t)(mbase + row) * CC + k0 + gc,
                  &As[buf][(wid * 64) * 8]);
    }
#pragma unroll
    for (int i = 0; i < 2; i++) {  // B tile: 128 rows x 4 slots = 512 units
      const int u = wid * 128 + i * 64 + l;
      const int row = u >> 2;
      const int gc = ((u & 3) ^ ((row >> 1) & 3)) * 8;
      gload_lds16(W + (size_t)(nbase + row) * CC + k0 + gc,
                  &Bs[buf][(wid * 128 + i * 64) * 8]);
    }
  };

  stage(0, 0);

  const int sA = (lhi ^ ((l15 >> 1) & 3)) << 3;

  constexpr int NK = CC / 32;
  for (int kt = 0; kt < NK; kt++) {
    const int cur = kt & 1;
    __syncthreads();
    if (kt + 1 < NK) stage(cur ^ 1, (kt + 1) * 32);

    bf16x8 af[2], bfr[4];
#pragma unroll
    for (int mi = 0; mi < 2; mi++)
      af[mi] = *(const bf16x8*)&As[cur][(wm * 32 + mi * 16 + l15) * 32 + sA];
#pragma unroll
    for (int ni = 0; ni < 4; ni++)
      bfr[ni] = *(const bf16x8*)&Bs[cur][(wn * 64 + ni * 16 + l15) * 32 + sA];
#pragma unroll
    for (int mi = 0; mi < 2; mi++)
#pragma unroll
      for (int ni = 0; ni < 4; ni++)
        acc[mi][ni] = mfma16(af[mi], bfr[ni], acc[mi][ni]);
  }

#pragma unroll
  for (int mi = 0; mi < 2; mi++)
#pragma unroll
    for (int ni = 0; ni < 4; ni++)
#pragma unroll
      for (int r = 0; r < 4; r++) {
        int grow = mbase + wm * 32 + mi * 16 + 4 * lhi + r;
        int gcol = nbase + wn * 64 + ni * 16 + l15;
        float val = (acc[mi][ni][r] + bias[gcol]) * scale;
        if (MODE == 0) {
          int T = 1 << tlog2;
          int bq = grow >> tlog2, tt = grow & (T - 1);
          int h = gcol >> 6, d = gcol & 63;
          size_t oidx = ((size_t)(bq * NH + h) * T + tt) * HD + d;
          ((unsigned short*)outp)[oidx] = f2bf(val);
        } else {
          ((float*)outp)[(size_t)grow * CC + gcol] = val;
        }
      }
}

// ---------------------------------------------------------------------------
// Fused K+V projection, 128x128 tile + global_load_lds: one A (ctx) tile
// feeds both Wk and Wv B-tiles (32 MFMA/K-step). K -> (b,h,t,d); V -> V^T.
// ---------------------------------------------------------------------------
__global__ __launch_bounds__(256, 2) void kv_gemm128(
    const unsigned short* __restrict__ A, const unsigned short* __restrict__ Wk,
    const unsigned short* __restrict__ Wv, const float* __restrict__ bk,
    const float* __restrict__ bv, unsigned short* __restrict__ k_out,
    unsigned short* __restrict__ v_out) {
  __shared__ __align__(16) unsigned short As[2][128 * 32];
  __shared__ __align__(16) unsigned short Bks[2][128 * 32];
  __shared__ __align__(16) unsigned short Bvs[2][128 * 32];

  const int tid = threadIdx.x;
  const int wid = tid >> 6, l = tid & 63, l15 = l & 15, lhi = l >> 4;
  const int wm = wid >> 1, wn = wid & 1;
  const int mbase = blockIdx.y * 128, nbase = blockIdx.x * 128;

  f32x4 acck[4][4], accv[4][4];
#pragma unroll
  for (int i = 0; i < 4; i++)
#pragma unroll
    for (int j = 0; j < 4; j++) { acck[i][j] = zero4(); accv[i][j] = zero4(); }

  auto stage = [&](int buf, int k0) {
#pragma unroll
    for (int i = 0; i < 2; i++) {
      const int u = wid * 128 + i * 64 + l;
      const int row = u >> 2;
      const int gc = ((u & 3) ^ ((row >> 1) & 3)) * 8;
      const int lo = (wid * 128 + i * 64) * 8;
      gload_lds16(A + (size_t)(mbase + row) * CC + k0 + gc, &As[buf][lo]);
      gload_lds16(Wk + (size_t)(nbase + row) * CC + k0 + gc, &Bks[buf][lo]);
      gload_lds16(Wv + (size_t)(nbase + row) * CC + k0 + gc, &Bvs[buf][lo]);
    }
  };

  stage(0, 0);

  const int sA = (lhi ^ ((l15 >> 1) & 3)) << 3;

  constexpr int NK = CC / 32;
  for (int kt = 0; kt < NK; kt++) {
    const int cur = kt & 1;
    __syncthreads();
    if (kt + 1 < NK) stage(cur ^ 1, (kt + 1) * 32);

    bf16x8 af[4], kf[4], vf[4];
#pragma unroll
    for (int mi = 0; mi < 4; mi++)
      af[mi] = *(const bf16x8*)&As[cur][(wm * 64 + mi * 16 + l15) * 32 + sA];
#pragma unroll
    for (int ni = 0; ni < 4; ni++) {
      kf[ni] = *(const bf16x8*)&Bks[cur][(wn * 64 + ni * 16 + l15) * 32 + sA];
      vf[ni] = *(const bf16x8*)&Bvs[cur][(wn * 64 + ni * 16 + l15) * 32 + sA];
    }
#pragma unroll
    for (int mi = 0; mi < 4; mi++)
#pragma unroll
      for (int ni = 0; ni < 4; ni++) {
        acck[mi][ni] = mfma16(af[mi], kf[ni], acck[mi][ni]);
        accv[mi][ni] = mfma16(af[mi], vf[ni], accv[mi][ni]);
      }
  }

#pragma unroll
  for (int mi = 0; mi < 4; mi++)
#pragma unroll
    for (int ni = 0; ni < 4; ni++)
#pragma unroll
      for (int r = 0; r < 4; r++) {
        int grow = mbase + wm * 64 + mi * 16 + 4 * lhi + r;
        int gcol = nbase + wn * 64 + ni * 16 + l15;
        int bq = grow >> 11, tt = grow & (TC - 1);
        int h = gcol >> 6, d = gcol & 63;
        float kv = acck[mi][ni][r] + bk[gcol];
        float vv = accv[mi][ni][r] + bv[gcol];
        k_out[((size_t)(bq * NH + h) * TC + tt) * HD + d] = f2bf(kv);
        v_out[((size_t)(bq * NH + h) * HD + d) * TC + tt] = f2bf(vv);
      }
}

// ---------------------------------------------------------------------------
// Flash attention fwd v10 — FINAL (reverted from v11: the one-tile-lagged
// softmax pipeline was null-to-negative, matching m253's finding that T15
// doesn't transfer to plain MFMA/VALU loops; cross-wave TLP already covers
// the serial chain). 8 waves; XCD swizzle (FETCH 135->20MB); swapped-QK^T
// in-register softmax; ones-MFMA row-sum; max3 tree; XOR-swizzled K/V LDS;
// exp2; defer-max; setprio; one barrier/iter.
// ---------------------------------------------------------------------------
__global__ __launch_bounds__(512) void attn_fwd(
    const unsigned short* __restrict__ Qw, const unsigned short* __restrict__ Kw,
    const unsigned short* __restrict__ Vtw, unsigned short* __restrict__ y_pre,
    float* __restrict__ m_ws, float* __restrict__ il_ws) {
  __shared__ __align__(16) unsigned short ktl[2][64 * 64];  // [buf][key][d] swz
  __shared__ __align__(16) unsigned short vtl[2][64 * 64];  // [buf][d][key] swz

  const int tid = threadIdx.x;
  const int wid = tid >> 6, l = tid & 63, l15 = l & 15, lhi = l >> 4;
  // XCD swizzle: linear id -> (qg,h,b) with XCD = p%8 = b
  const int p = blockIdx.x + (TX / 128) * (blockIdx.y + NH * blockIdx.z);
  const int qg = p >> 6, h = (p >> 3) & 7, b = p & 7;
  const int qbase = qg * 128 + wid * 16;

  const unsigned short* Qh = Qw + (size_t)(b * NH + h) * TX * HD;
  const unsigned short* Kh = Kw + (size_t)(b * NH + h) * TC * HD;
  const unsigned short* Vt = Vtw + (size_t)(b * NH + h) * TC * HD;  // (d, t)

  bf16x8 aq0 = *(const bf16x8*)(Qh + (size_t)(qbase + l15) * HD + lhi * 8);
  bf16x8 aq1 = *(const bf16x8*)(Qh + (size_t)(qbase + l15) * HD + 32 + lhi * 8);

  bf16x8 ones;
#pragma unroll
  for (int j = 0; j < 8; j++) ones[j] = (short)0x3F80;  // bf16 1.0

  f32x4 accy[4];
#pragma unroll
  for (int db = 0; db < 4; db++) accy[db] = zero4();
  f32x4 accl = zero4();  // P-row-sum accumulator (ones-MFMA)
  float mrun = -1e30f;

  const int sl0 = l15 + ((lhi & 1) << 5);
  const int sl1 = sl0 + 16;
  const bool sel = ((lhi >> 1) & 1) != 0;

  const int rs0 = (lhi ^ (l15 & 7)) << 3;
  const int rs1 = ((lhi ^ 4) ^ (l15 & 7)) << 3;

  const int sr = tid >> 3;
  const int ssw = ((tid & 7) ^ (sr & 7)) << 3;
  const int sc0 = (tid & 7) * 8;

  bf16x8 kr = *(const bf16x8*)(Kh + (size_t)sr * HD + sc0);
  bf16x8 vp = *(const bf16x8*)(Vt + (size_t)sr * TC + sc0);
  *(bf16x8*)&ktl[0][sr * 64 + ssw] = kr;
  *(bf16x8*)&vtl[0][sr * 64 + ssw] = vp;
  __syncthreads();

  constexpr int NT = TC / 64;
  for (int kt = 0; kt < NT; kt++) {
    const int cur = kt & 1;

    if (kt + 1 < NT) {
      const int keyn = (kt + 1) * 64;
      kr = *(const bf16x8*)(Kh + (size_t)(keyn + sr) * HD + sc0);
      vp = *(const bf16x8*)(Vt + (size_t)sr * TC + keyn + sc0);
    }

    f32x4 s[4];
    __builtin_amdgcn_s_setprio(1);
#pragma unroll
    for (int kb = 0; kb < 4; kb++) {
      bf16x8 bk0 = *(const bf16x8*)&ktl[cur][(kb * 16 + l15) * 64 + rs0];
      bf16x8 bk1 = *(const bf16x8*)&ktl[cur][(kb * 16 + l15) * 64 + rs1];
      f32x4 a = zero4();
      a = mfma16(bk0, aq0, a);
      a = mfma16(bk1, aq1, a);
      s[kb] = a;
    }
    __builtin_amdgcn_s_setprio(0);

    float t0 = max3f(s[0][0], s[0][1], s[0][2]);
    float t1 = max3f(s[0][3], s[1][0], s[1][1]);
    float t2 = max3f(s[1][2], s[1][3], s[2][0]);
    float t3 = max3f(s[2][1], s[2][2], s[2][3]);
    float t4 = max3f(s[3][0], s[3][1], s[3][2]);
    float mx = fmaxf(max3f(t0, t1, t2), max3f(t3, t4, s[3][3]));
    mx = fmaxf(mx, __shfl_xor(mx, 16));
    mx = fmaxf(mx, __shfl_xor(mx, 32));

    if (__any(mx - mrun > 7.0f)) {
      float mn = fmaxf(mrun, mx);
      float sc = exp2f(mrun - mn);
      mrun = mn;
#pragma unroll
      for (int r = 0; r < 4; r++) accl[r] *= sc;
#pragma unroll
      for (int db = 0; db < 4; db++)
#pragma unroll
        for (int r = 0; r < 4; r++) accy[db][r] *= sc;
    }

    float p4[4][4];
#pragma unroll
    for (int kb = 0; kb < 4; kb++)
#pragma unroll
      for (int r = 0; r < 4; r++) p4[kb][r] = exp2f(s[kb][r] - mrun);

    unsigned pkw[4][2];
#pragma unroll
    for (int kb = 0; kb < 4; kb++) {
      pkw[kb][0] = cvtpk(p4[kb][0], p4[kb][1]);
      pkw[kb][1] = cvtpk(p4[kb][2], p4[kb][3]);
    }
    unsigned a00 = (unsigned)__shfl((int)pkw[0][0], sl0);
    unsigned a01 = (unsigned)__shfl((int)pkw[0][1], sl0);
    unsigned a10 = (unsigned)__shfl((int)pkw[1][0], sl0);
    unsigned a11 = (unsigned)__shfl((int)pkw[1][1], sl0);
    unsigned c00 = (unsigned)__shfl((int)pkw[0][0], sl1);
    unsigned c01 = (unsigned)__shfl((int)pkw[0][1], sl1);
    unsigned c10 = (unsigned)__shfl((int)pkw[1][0], sl1);
    unsigned c11 = (unsigned)__shfl((int)pkw[1][1], sl1);
    unsigned e00 = (unsigned)__shfl((int)pkw[2][0], sl0);
    unsigned e01 = (unsigned)__shfl((int)pkw[2][1], sl0);
    unsigned e10 = (unsigned)__shfl((int)pkw[3][0], sl0);
    unsigned e11 = (unsigned)__shfl((int)pkw[3][1], sl0);
    unsigned g00 = (unsigned)__shfl((int)pkw[2][0], sl1);
    unsigned g01 = (unsigned)__shfl((int)pkw[2][1], sl1);
    unsigned g10 = (unsigned)__shfl((int)pkw[3][0], sl1);
    unsigned g11 = (unsigned)__shfl((int)pkw[3][1], sl1);
    union { unsigned u[4]; bf16x8 v; } B0, B1;
    B0.u[0] = sel ? a10 : a00;
    B0.u[1] = sel ? a11 : a01;
    B0.u[2] = sel ? c10 : c00;
    B0.u[3] = sel ? c11 : c01;
    B1.u[0] = sel ? e10 : e00;
    B1.u[1] = sel ? e11 : e01;
    B1.u[2] = sel ? g10 : g00;
    B1.u[3] = sel ? g11 : g01;

    __builtin_amdgcn_s_setprio(1);
#pragma unroll
    for (int db = 0; db < 4; db++) {
      bf16x8 bv0 = *(const bf16x8*)&vtl[cur][(db * 16 + l15) * 64 + rs0];
      bf16x8 bv1 = *(const bf16x8*)&vtl[cur][(db * 16 + l15) * 64 + rs1];
      accy[db] = mfma16(bv0, B0.v, accy[db]);
      accy[db] = mfma16(bv1, B1.v, accy[db]);
    }
    accl = mfma16(ones, B0.v, accl);
    accl = mfma16(ones, B1.v, accl);
    __builtin_amdgcn_s_setprio(0);

    if (kt + 1 < NT) {
      const int nxt = cur ^ 1;
      *(bf16x8*)&ktl[nxt][sr * 64 + ssw] = kr;
      *(bf16x8*)&vtl[nxt][sr * 64 + ssw] = vp;
    }
    __syncthreads();
  }

  const float il = 1.f / accl[0];

#pragma unroll
  for (int db = 0; db < 4; db++) {
    bf16x4 o;
#pragma unroll
    for (int r = 0; r < 4; r++) o[r] = (short)f2bf(accy[db][r] * il);
    *(bf16x4*)(y_pre + (size_t)(b * TX + qbase + l15) * CC + h * HD + db * 16 +
               4 * lhi) = o;
  }
  if (lhi == 0) {
    int idx = (b * NH + h) * TX + qbase + l15;
    m_ws[idx] = mrun;
    il_ws[idx] = il;
  }
}

// ---------------------------------------------------------------------------
// att_mean v6 — FINAL (R15 spill, R17 occupancy, R20 spill; this operating
// point — KVBLK=64, 2-state Q, ~104 VGPR, 16KB LDS — is the feasibility
// pocket). 8 waves / 512 threads = 128 q-rows x 64 keys; per-head K tile in
// XOR-swizzled LDS (double-buffered, prefetch top / commit bottom, one
// barrier per head); p = 2^(s-m) * (1/l).
// ---------------------------------------------------------------------------
__global__ __launch_bounds__(512) void att_mean_k(
    const unsigned short* __restrict__ Qw, const unsigned short* __restrict__ Kw,
    const float* __restrict__ m_ws, const float* __restrict__ il_ws,
    float* __restrict__ attm) {
  __shared__ __align__(16) unsigned short ktl[2][64 * 64];  // [buf][key][d] swz

  const int tid = threadIdx.x;
  const int wid = tid >> 6, l = tid & 63, l15 = l & 15, lhi = l >> 4;
  const int qbase = blockIdx.x * 128 + wid * 16;  // x = q tile (fastest)
  const int keyb = blockIdx.y * 64;               // y = key tile
  const int b = blockIdx.z;

  const unsigned short* Qb = Qw + (size_t)b * NH * TX * HD;
  const unsigned short* Kb = Kw + (size_t)b * NH * TC * HD;

  const int rs0 = (lhi ^ (l15 & 7)) << 3;
  const int rs1 = ((lhi ^ 4) ^ (l15 & 7)) << 3;

  const int sr = tid >> 3;
  const int ssw = ((tid & 7) ^ (sr & 7)) << 3;
  const int sc0 = (tid & 7) * 8;

  bf16x8 aq0[2], aq1[2];
  f32x4 mm[2], ii[2];

  auto load_q = [&](int h, int p) {
    const unsigned short* qp =
        Qb + ((size_t)h * TX + qbase + l15) * HD + lhi * 8;
    aq0[p] = *(const bf16x8*)qp;
    aq1[p] = *(const bf16x8*)(qp + 32);
    mm[p] = *(const f32x4*)(m_ws + (size_t)(b * NH + h) * TX + qbase + 4 * lhi);
    ii[p] = *(const f32x4*)(il_ws + (size_t)(b * NH + h) * TX + qbase + 4 * lhi);
  };

  bf16x8 kr = *(const bf16x8*)(Kb + ((size_t)keyb + sr) * HD + sc0);
  load_q(0, 0);
  *(bf16x8*)&ktl[0][sr * 64 + ssw] = kr;
  __syncthreads();

  f32x4 am[4];
#pragma unroll
  for (int kb = 0; kb < 4; kb++) am[kb] = zero4();

#pragma unroll
  for (int h = 0; h < NH; h++) {
    const int cur = h & 1;

    if (h + 1 < NH) {
      kr = *(const bf16x8*)(Kb + ((size_t)(h + 1) * TC + keyb + sr) * HD + sc0);
      load_q(h + 1, cur ^ 1);
    }

#pragma unroll
    for (int kb = 0; kb < 4; kb++) {
      bf16x8 bk0 = *(const bf16x8*)&ktl[cur][(kb * 16 + l15) * 64 + rs0];
      bf16x8 bk1 = *(const bf16x8*)&ktl[cur][(kb * 16 + l15) * 64 + rs1];
      f32x4 a = zero4();
      a = mfma16(aq0[cur], bk0, a);
      a = mfma16(aq1[cur], bk1, a);
#pragma unroll
      for (int r = 0; r < 4; r++)
        am[kb][r] += exp2f(a[r] - mm[cur][r]) * ii[cur][r];
    }

    if (h + 1 < NH) {
      const int nxt = cur ^ 1;
      *(bf16x8*)&ktl[nxt][sr * 64 + ssw] = kr;
    }
    __syncthreads();
  }

#pragma unroll
  for (int kb = 0; kb < 4; kb++)
#pragma unroll
    for (int r = 0; r < 4; r++) {
      int trow = qbase + 4 * lhi + r;
      attm[(size_t)(b * TX + trow) * TC + keyb + kb * 16 + l15] = am[kb][r] * 0.125f;
    }
}

// ---------------------------------------------------------------------------
extern "C" void kernel_launch(void* const* d_in, const int* in_sizes, int n_in,
                              void* d_out, int out_size, void* d_ws, size_t ws_size,
                              hipStream_t stream) {
  const float* x   = (const float*)d_in[0];
  const float* ctx = (const float*)d_in[1];
  const float* Wq  = (const float*)d_in[2];
  const float* bq  = (const float*)d_in[3];
  const float* Wk  = (const float*)d_in[4];
  const float* bk  = (const float*)d_in[5];
  const float* Wv  = (const float*)d_in[6];
  const float* bv  = (const float*)d_in[7];
  const float* Wo  = (const float*)d_in[8];
  const float* bo  = (const float*)d_in[9];

  float* y_out = (float*)d_out;                       // (B, Tx, C)
  float* attm  = y_out + (size_t)Bb * TX * CC;        // (B, Tx, Tc)

  // workspace layout (16B-aligned), ~53 MB total:
  unsigned short* q_ws = (unsigned short*)d_ws;                  // B*NH*TX*HD bf16
  unsigned short* k_ws = q_ws + (size_t)Bb * NH * TX * HD;       // B*NH*TC*HD bf16
  unsigned short* v_ws = k_ws + (size_t)Bb * NH * TC * HD;       // B*NH*TC*HD bf16 (V^T)
  float* m_ws  = (float*)(v_ws + (size_t)Bb * NH * TC * HD);     // B*NH*TX f32
  float* il_ws = m_ws + (size_t)Bb * NH * TX;                    // B*NH*TX f32
  unsigned short* y_pre = (unsigned short*)(il_ws + (size_t)Bb * NH * TX);  // B*TX*CC bf16
  unsigned short* wb = y_pre + (size_t)Bb * TX * CC;             // 4x CC*CC bf16
  unsigned short* wbq = wb, *wbk = wb + CC * CC, *wbv = wb + 2 * CC * CC,
                 *wbo = wb + 3 * CC * CC;

  // bf16 input overlays (consumed before their regions are overwritten):
  unsigned short* xb = k_ws;              // read by Q-GEMM, then kv_gemm overwrites
  unsigned short* cb = (unsigned short*)attm;  // read by kv_gemm, att_mean_k overwrites

  const int NX8 = Bb * TX * CC / 8, NC8 = Bb * TC * CC / 8, NW8 = CC * CC / 8;
  cvt_all<<<dim3(2048), 256, 0, stream>>>(x, xb, NX8, ctx, cb, NC8,
                                          Wq, wbq, NW8, Wk, wbk, NW8,
                                          Wv, wbv, NW8, Wo, wbo, NW8);

  // Q pre-scaled by log2(e)/sqrt(hd) so attention exp is bare v_exp_f32 (2^x)
  gemm64m<0><<<dim3(CC / 128, (Bb * TX) / 64), 256, 0, stream>>>(
      xb, wbq, bq, q_ws, 10, 0.125f * LOG2E);
  kv_gemm128<<<dim3(CC / 128, (Bb * TC) / 128), 256, 0, stream>>>(
      cb, wbk, wbv, bk, bv, k_ws, v_ws);
  attn_fwd<<<dim3(TX / 128, NH, Bb), 512, 0, stream>>>(q_ws, k_ws, v_ws, y_pre, m_ws, il_ws);
  att_mean_k<<<dim3(TX / 128, TC / 64, Bb), 512, 0, stream>>>(q_ws, k_ws, m_ws, il_ws, attm);
  gemm64m<1><<<dim3(CC / 128, (Bb * TX) / 64), 256, 0, stream>>>(
      y_pre, wbo, bo, y_out, 10, 1.0f);
}